// Round 3
// baseline (549.674 us; speedup 1.0000x reference)
//
#include <hip/hip_runtime.h>

typedef unsigned short u16;
typedef _Float16 half8 __attribute__((ext_vector_type(8)));
typedef __attribute__((ext_vector_type(4))) float f32x4;

constexpr int NB = 4;        // batch
constexpr int S  = 4096;     // sequence
constexpr int D  = 1024;     // model dim

__device__ __forceinline__ u16 h2u(_Float16 h) {
    union { _Float16 h; u16 u; } v; v.h = h; return v.u;
}

// Async global->LDS, 16 B per lane. LDS destination is wave-uniform
// base + lane*16 (lane-linear chunk order).
__device__ __forceinline__ void async16(const void* g, void* l) {
    __builtin_amdgcn_global_load_lds(
        (const __attribute__((address_space(1))) unsigned int*)g,
        (__attribute__((address_space(3))) unsigned int*)l, 16, 0, 0);
}

#define BAR()  __builtin_amdgcn_s_barrier()
#define SFEN() __builtin_amdgcn_sched_barrier(0)

// 16 MFMA for quadrant (QM,QN): 4 M-frags x 2 N-frags x 2 K-halves.
#define MF(AF, BF, QM, QN)                                                     \
  do {                                                                         \
    _Pragma("unroll") for (int m_ = 0; m_ < 4; ++m_)                           \
    _Pragma("unroll") for (int n_ = 0; n_ < 2; ++n_)                           \
    _Pragma("unroll") for (int k_ = 0; k_ < 2; ++k_)                           \
      acc[(QM)*4 + m_][(QN)*2 + n_] = __builtin_amdgcn_mfma_f32_16x16x32_f16(  \
          AF[m_][k_], BF[n_][k_], acc[(QM)*4 + m_][(QN)*2 + n_], 0, 0, 0);     \
  } while (0)

// Fragment reads off precomputed per-lane bases; (qm,m)/(qn,n) are
// compile-time -> fold into the ds_read_b128 immediate offset.
#define RDA(dst, bp0, bp1, qm)                                                 \
  _Pragma("unroll") for (int m_ = 0; m_ < 4; ++m_) {                           \
    dst[m_][0] = *(const half8*)(bp0 + (qm) * 4096 + m_ * 1024);               \
    dst[m_][1] = *(const half8*)(bp1 + (qm) * 4096 + m_ * 1024); }
#define RDB(dst, bp0, bp1, qn)                                                 \
  _Pragma("unroll") for (int n_ = 0; n_ < 2; ++n_) {                           \
    dst[n_][0] = *(const half8*)(bp0 + (qn) * 2048 + n_ * 1024);               \
    dst[n_][1] = *(const half8*)(bp1 + (qn) * 2048 + n_ * 1024); }

// ---------------------------------------------------------------------------
// One half-iteration (4 single-barrier windows = one K-tile).
// RAd/RBd: LDS stage dests of the buffer being COMPUTED (R). OAd/OBd: other.
// rA0/rA1/rB0/rB1: read base ptrs (kk=0/1) of R. KO: k staged into O (tile
// t+1 completion). KN: k staged into R (tile t+2 start).
//
// Publish ledger (single vmcnt(4) at end-D): steady state entering half h
// the outstanding loads are [h-1.C, h-1.D] (4). A..D each add 2; end-D
// vmcnt(4) drains {h-1.C, h-1.D, h.A, h.B}. R(h).qm1/qn1 staged h-1.A/B,
// R(h).qm0/qn0 staged h-2.C/D -- ALL drained by end of half h-1.
// Flight >= 2 windows per load (h.B is tightest).
// Overwrite ledger: every stage targets a slot last READ >=2 barriers
// earlier: W_A stage O.qm1 (read h-1.W_B, 3 bars); W_B stage O.qn1 (read
// h-1.W_A, 4 bars); W_C stage R.qm0 (read h.W_A, 2 bars); W_D stage R.qn0
// (read h.W_A, 3 bars).
// Reads b1/a1 sit INSIDE the W_A/W_B MFMA windows (shadowed under MFMA
// issue gaps via compiler lgkmcnt); only W_A's 12 reads are exposed.
// ---------------------------------------------------------------------------
#define HALF(RAd, RBd, OAd, OBd, rA0, rA1, rB0, rB1, KO, KN)                   \
  { /* W_A: MFMA quadrant (0,0) */                                             \
    RDA(a0, rA0, rA1, 0)                                                       \
    RDB(b0, rB0, rB1, 0)                                                       \
    issue(Am, OAd, rsA + 64, KO);                                              \
    __builtin_amdgcn_s_setprio(1); MF(a0, b0, 0, 0);                           \
    __builtin_amdgcn_s_setprio(0);                                             \
    RDB(b1, rB0, rB1, 1)                                                       \
    BAR(); SFEN();                                                             \
    /* W_B: quadrant (0,1) */                                                  \
    issue(Bm, OBd, rsB + 32, KO);                                              \
    __builtin_amdgcn_s_setprio(1); MF(a0, b1, 0, 1);                           \
    __builtin_amdgcn_s_setprio(0);                                             \
    RDA(a1, rA0, rA1, 1)                                                       \
    BAR(); SFEN();                                                             \
    /* W_C: quadrant (1,0) */                                                  \
    issue(Am, RAd, rsA, KN);                                                   \
    __builtin_amdgcn_s_setprio(1); MF(a1, b0, 1, 0);                           \
    __builtin_amdgcn_s_setprio(0);                                             \
    BAR(); SFEN();                                                             \
    /* W_D: quadrant (1,1) */                                                  \
    issue(Bm, RBd, rsB, KN);                                                   \
    __builtin_amdgcn_s_setprio(1); MF(a1, b1, 1, 1);                           \
    __builtin_amdgcn_s_setprio(0);                                             \
    asm volatile("s_waitcnt vmcnt(4)" ::: "memory");                           \
    BAR(); SFEN();                                                             \
  }

// ---------------------------------------------------------------------------
// 256x256x(K) NT GEMM core, single-barrier-window counted-vmcnt schedule.
// A [256 x K] fp16 row-major (pre-offset), B [256 x K] fp16 row-major
// (pre-offset). 512 threads = 8 waves (2M x 4N); per-wave 128x64 output,
// acc[8][4] f32x4. LDS: double buffer x (A[256][64] + B[256][64]) = 128 KiB.
//
// Row = 64 halfs = 128 B = full bank period. XOR swizzle: global chunk gc of
// row r stored at chunk gc ^ (r&7), applied on the SOURCE address
// (lane-linear LDS dest, required by global_load_lds). Read addresses come
// from 8 precomputed per-lane bases (A/B x kk x buffer); (qm,m)/(qn,n)
// become ds_read immediate offsets (max 14336 B < 64 KiB).
//
// Fragment layouts (HW-verified, carried from the 128^2 kernel):
//   A: lane holds A[m=lane&15][kk*32 + (lane>>4)*8 + j]
//   C: acc[mi][ni][r] = C[wm*128+mi*16+(lane>>4)*4+r][wn*64+ni*16+(lane&15)]
// ---------------------------------------------------------------------------
__device__ __forceinline__ void gemm256(
    const u16* __restrict__ Am, const u16* __restrict__ Bm, const int K,
    u16* lds, f32x4 acc[8][4])
{
    const int tid  = threadIdx.x;
    const int lane = tid & 63;
    const int w    = tid >> 6;          // 0..7
    const int wm   = w >> 2;            // 0..1
    const int wn   = w & 3;             // 0..3
    const int quad = lane >> 4;
    const int lrow = lane & 15;
    const int s7   = lrow & 7;
    const int rl   = lane >> 3;                    // staging row-in-group
    const int gc8  = ((lane & 7) ^ rl) * 8;        // swizzled source chunk
    const int rsA  = (wm << 7) + ((w & 3) << 4);   // A slot row-start
    const int rsB  = ((w >> 1) << 6) + ((w & 1) << 4);   // B slot row-start

    u16* const As0 = lds;
    u16* const Bs0 = lds + 16384;
    u16* const As1 = lds + 32768;
    u16* const Bs1 = lds + 49152;

    // Per-lane read bases (halfs). lt0/lt1 = lane term for kk=0/1.
    const int lt0 = lrow * 64 + ((quad ^ s7) * 8);
    const int lt1 = lrow * 64 + (((4 + quad) ^ s7) * 8);
    const u16* const bA00 = As0 + wm * 8192 + lt0;
    const u16* const bA01 = As0 + wm * 8192 + lt1;
    const u16* const bA10 = As1 + wm * 8192 + lt0;
    const u16* const bA11 = As1 + wm * 8192 + lt1;
    const u16* const bB00 = Bs0 + wn * 4096 + lt0;
    const u16* const bB01 = Bs0 + wn * 4096 + lt1;
    const u16* const bB10 = Bs1 + wn * 4096 + lt0;
    const u16* const bB11 = Bs1 + wn * 4096 + lt1;

    auto issue = [&](const u16* M, u16* dst, int rs, int k0) {
        async16(M + (size_t)(rs + rl) * K + k0 + gc8,
                dst + (size_t)(rs)     * 64 + (size_t)lane * 8);
        async16(M + (size_t)(rs + 8 + rl) * K + k0 + gc8,
                dst + (size_t)(rs + 8) * 64 + (size_t)lane * 8);
    };

    // Prologue: t0 all four slot-groups + t1 qm0/qn0 (playing h-1.C/D).
    issue(Am, As0, rsA,      0);
    issue(Bm, Bs0, rsB,      0);
    issue(Am, As0, rsA + 64, 0);
    issue(Bm, Bs0, rsB + 32, 0);
    issue(Am, As1, rsA,      64);
    issue(Bm, Bs1, rsB,      64);
    asm volatile("s_waitcnt vmcnt(4)" ::: "memory");   // all of t0 landed
    BAR(); SFEN();

    half8 a0[4][2], a1[4][2], b0[2][2], b1[2][2];
    const int km = K - 1;               // K is a power of two (1024 / 4096)
    const int NI = K >> 7;              // 2 K-tiles (BK=64) per iteration
    for (int it = 0; it < NI; ++it) {
        const int kb  = it << 7;
        const int t1k = (kb + 64)  & km;      // real
        const int t2k = (kb + 128) & km;      // wraps to dummy on last iter
        const int t3k = (kb + 192) & km;      // wraps to dummy on last iter
        HALF(As0, Bs0, As1, Bs1, bA00, bA01, bB00, bB01, t1k, t2k)
        HALF(As1, Bs1, As0, Bs0, bA10, bA11, bB10, bB11, t2k, t3k)
    }
    // Trailing (wrapped) prefetches stay in flight; they only touch LDS
    // slots that are never read again. Epilogue is registers + global only.
}

// ---------------------------------------------------------------------------
// 0) fp32 -> fp16 cast, 8 elems/thread
// ---------------------------------------------------------------------------
__global__ __launch_bounds__(256) void cvt_kernel(
    const float* __restrict__ in, u16* __restrict__ out, int n8)
{
    const int i = blockIdx.x * 256 + threadIdx.x;
    if (i >= n8) return;
    const float4 a = *(const float4*)(in + (size_t)i * 8);
    const float4 b = *(const float4*)(in + (size_t)i * 8 + 4);
    half8 h;
    h[0] = (_Float16)a.x; h[1] = (_Float16)a.y;
    h[2] = (_Float16)a.z; h[3] = (_Float16)a.w;
    h[4] = (_Float16)b.x; h[5] = (_Float16)b.y;
    h[6] = (_Float16)b.z; h[7] = (_Float16)b.w;
    *(half8*)(out + (size_t)i * 8) = h;
}

// ---------------------------------------------------------------------------
// 1) QKV projection: out[s,e] = sum_d x16[s,d] * W16[e,d]  (NT, K=D)
// grid (64, 4, 3); z picks {Wq,Wk,Wv} -> {Q,K,V} (fp16). XCD-chunk swizzle.
// ---------------------------------------------------------------------------
__global__ __launch_bounds__(512, 2) void qkv_kernel(
    const u16* __restrict__ x16, const u16* __restrict__ W16,
    u16* __restrict__ Q, u16* __restrict__ Kb, u16* __restrict__ V)
{
    __shared__ __align__(16) u16 lds[65536];          // 128 KiB
    // bijective XCD swizzle: nwg=768, cpx=96
    const int lin = blockIdx.x + (blockIdx.y << 6) + (blockIdx.z << 8);
    const int swz = (lin & 7) * 96 + (lin >> 3);
    const int bx = swz & 63, by = (swz >> 6) & 3, bz = swz >> 8;

    const int tile_m = bx * 256;
    const int tile_n = by * 256;
    const u16* W = W16 + (size_t)bz * D * D;
    u16* out = (bz == 0) ? Q : (bz == 1) ? Kb : V;

    f32x4 acc[8][4];
#pragma unroll
    for (int i = 0; i < 8; ++i)
#pragma unroll
        for (int j = 0; j < 4; ++j) acc[i][j] = (f32x4)0.0f;

    gemm256(x16 + (size_t)tile_m * D, W + (size_t)tile_n * D, D, lds, acc);

    const int tid = threadIdx.x, lane = tid & 63, w = tid >> 6;
    const int quad = lane >> 4, lrow = lane & 15;
    const int wm = w >> 2, wn = w & 3;
#pragma unroll
    for (int mi = 0; mi < 8; ++mi)
#pragma unroll
        for (int r = 0; r < 4; ++r) {
            const int row = tile_m + wm * 128 + mi * 16 + quad * 4 + r;
#pragma unroll
            for (int ni = 0; ni < 4; ++ni) {
                const int col = tile_n + wn * 64 + ni * 16 + lrow;
                out[(size_t)row * D + col] = h2u((_Float16)acc[mi][ni][r]);
            }
        }
}

// ---------------------------------------------------------------------------
// 2) Transpose V [NB*S x D] -> Vt [NB][D][S] (64x64 LDS tiles, fp16 bits)
// ---------------------------------------------------------------------------
__global__ __launch_bounds__(256) void transpose_v(
    const u16* __restrict__ V, u16* __restrict__ Vt)
{
    __shared__ u16 t[64][72];                      // 144B row stride (16B-mult)
    const int sg = blockIdx.x * 64;                // global row (b,s)
    const int b  = sg >> 12;
    const int s0 = sg & (S - 1);
    const int e0 = blockIdx.y * 64;
    const int tid = threadIdx.x;
#pragma unroll
    for (int p = 0; p < 2; ++p) {
        const int v  = tid + 256 * p;              // 0..511
        const int sr = v >> 3, sc = (v & 7) * 8;
        half8 vec = *(const half8*)(V + (size_t)(sg + sr) * D + e0 + sc);
        *(half8*)&t[sr][sc] = vec;
    }
    __syncthreads();
#pragma unroll
    for (int p = 0; p < 2; ++p) {
        const int v  = tid + 256 * p;
        const int e  = v >> 3, s8 = (v & 7) * 8;
        u16 o[8];
#pragma unroll
        for (int j = 0; j < 8; ++j) o[j] = t[s8 + j][e];
        *(uint4*)(Vt + (size_t)b * D * S + (size_t)(e0 + e) * S + s0 + s8) = *(const uint4*)o;
    }
}

// ---------------------------------------------------------------------------
// 3) scores: P[b][q][k] = Q_b[q,:] . K_b[k,:]   (NT, K=D), grid (16,16,4)
// ---------------------------------------------------------------------------
__global__ __launch_bounds__(512, 2) void scores_kernel(
    const u16* __restrict__ Q, const u16* __restrict__ Kb, u16* __restrict__ P)
{
    __shared__ __align__(16) u16 lds[65536];
    // bijective XCD swizzle: nwg=1024, cpx=128
    const int lin = blockIdx.x + ((blockIdx.y + (blockIdx.z << 4)) << 4);
    const int swz = ((lin & 7) << 7) + (lin >> 3);
    const int bx = swz & 15, by = (swz >> 4) & 15, bz = swz >> 8;

    const int b = bz;
    const int tile_m = bx * 256;
    const int tile_n = by * 256;
    const u16* Ab = Q  + (size_t)b * S * D + (size_t)tile_m * D;
    const u16* Bv = Kb + (size_t)b * S * D + (size_t)tile_n * D;

    f32x4 acc[8][4];
#pragma unroll
    for (int i = 0; i < 8; ++i)
#pragma unroll
        for (int j = 0; j < 4; ++j) acc[i][j] = (f32x4)0.0f;

    gemm256(Ab, Bv, D, lds, acc);

    u16* Pb = P + (size_t)b * S * S;
    const int tid = threadIdx.x, lane = tid & 63, w = tid >> 6;
    const int quad = lane >> 4, lrow = lane & 15;
    const int wm = w >> 2, wn = w & 3;
#pragma unroll
    for (int mi = 0; mi < 8; ++mi)
#pragma unroll
        for (int r = 0; r < 4; ++r) {
            const int row = tile_m + wm * 128 + mi * 16 + quad * 4 + r;
#pragma unroll
            for (int ni = 0; ni < 4; ++ni) {
                const int col = tile_n + wn * 64 + ni * 16 + lrow;
                Pb[(size_t)row * S + col] = h2u((_Float16)acc[mi][ni][r]);
            }
        }
}

// ---------------------------------------------------------------------------
// 4) softmax over each row of P (4096 fp16), in place. 256 thr x 16 elems.
// ---------------------------------------------------------------------------
__global__ __launch_bounds__(256) void softmax_kernel(u16* __restrict__ P)
{
    const size_t row = blockIdx.x;                 // 0..NB*S-1 (flat: stride S)
    u16* p = P + row * S;
    const int tid = threadIdx.x;

    half8 h0 = *(const half8*)(p + tid * 16);
    half8 h1 = *(const half8*)(p + tid * 16 + 8);
    float v[16];
#pragma unroll
    for (int i = 0; i < 8; ++i) { v[i] = (float)h0[i]; v[8 + i] = (float)h1[i]; }

    float m = v[0];
#pragma unroll
    for (int i = 1; i < 16; ++i) m = fmaxf(m, v[i]);
#pragma unroll
    for (int off = 32; off > 0; off >>= 1) m = fmaxf(m, __shfl_xor(m, off));

    __shared__ float redm[4], reds[4];
    const int wid = tid >> 6;
    if ((tid & 63) == 0) redm[wid] = m;
    __syncthreads();
    m = fmaxf(fmaxf(redm[0], redm[1]), fmaxf(redm[2], redm[3]));

    float e[16], s = 0.f;
#pragma unroll
    for (int i = 0; i < 16; ++i) { e[i] = __expf(v[i] - m); s += e[i]; }
#pragma unroll
    for (int off = 32; off > 0; off >>= 1) s += __shfl_xor(s, off);
    if ((tid & 63) == 0) reds[wid] = s;
    __syncthreads();
    s = reds[0] + reds[1] + reds[2] + reds[3];
    const float inv = 1.0f / s;                    // s >= 1 always

#pragma unroll
    for (int i = 0; i < 8; ++i) {
        h0[i] = (_Float16)(e[i] * inv);
        h1[i] = (_Float16)(e[8 + i] * inv);
    }
    *(half8*)(p + tid * 16)     = h0;
    *(half8*)(p + tid * 16 + 8) = h1;
}

// ---------------------------------------------------------------------------
// 5) PV: y[b,q,d] = sum_k P[b,q,k]*Vt[b,d,k] + x[b,q,d]; y -> d_out (fp32).
//    grid (16,4,4). Row norms recomputed later by normalize_kernel.
// ---------------------------------------------------------------------------
__global__ __launch_bounds__(512, 2) void pv_kernel(
    const u16* __restrict__ P, const u16* __restrict__ Vt,
    const float* __restrict__ x, float* __restrict__ y)
{
    __shared__ __align__(16) u16 lds[65536];
    // bijective XCD swizzle: nwg=256, cpx=32
    const int lin = blockIdx.x + (blockIdx.y << 4) + (blockIdx.z << 6);
    const int swz = ((lin & 7) << 5) + (lin >> 3);
    const int bx = swz & 15, by = (swz >> 4) & 3, bz = swz >> 6;

    const int b = bz;
    const int tile_m = bx * 256;                   // query tile
    const int tile_n = by * 256;                   // d tile
    const u16* Ab = P  + (size_t)b * S * S + (size_t)tile_m * S;
    const u16* Bv = Vt + (size_t)b * D * S + (size_t)tile_n * S;

    f32x4 acc[8][4];
#pragma unroll
    for (int i = 0; i < 8; ++i)
#pragma unroll
        for (int j = 0; j < 4; ++j) acc[i][j] = (f32x4)0.0f;

    gemm256(Ab, Bv, S, lds, acc);

    const int tid = threadIdx.x, lane = tid & 63, w = tid >> 6;
    const int quad = lane >> 4, lrow = lane & 15;
    const int wm = w >> 2, wn = w & 3;

#pragma unroll
    for (int mi = 0; mi < 8; ++mi)
#pragma unroll
        for (int r = 0; r < 4; ++r) {
            const int row = tile_m + wm * 128 + mi * 16 + quad * 4 + r;
            const size_t base = ((size_t)b * S + row) * D;
#pragma unroll
            for (int ni = 0; ni < 4; ++ni) {
                const int col = tile_n + wn * 64 + ni * 16 + lrow;
                y[base + col] = acc[mi][ni][r] + x[base + col];
            }
        }
}

// ---------------------------------------------------------------------------
// 6) normalize rows of y (fp32) in place: block per row, 256 thr x float4.
// ---------------------------------------------------------------------------
__global__ __launch_bounds__(256) void normalize_kernel(float* __restrict__ y)
{
    const size_t row = blockIdx.x;
    const int tid = threadIdx.x;
    float4* p = (float4*)(y + row * D) + tid;

    float4 v = *p;
    float ss = v.x * v.x + v.y * v.y + v.z * v.z + v.w * v.w;
#pragma unroll
    for (int off = 32; off > 0; off >>= 1) ss += __shfl_xor(ss, off);

    __shared__ float red[4];
    const int wid = tid >> 6;
    if ((tid & 63) == 0) red[wid] = ss;
    __syncthreads();
    const float inv = rsqrtf(red[0] + red[1] + red[2] + red[3]);

    v.x *= inv; v.y *= inv; v.z *= inv; v.w *= inv;
    *p = v;
}

// ---------------------------------------------------------------------------
// Workspace layout (224 MiB total, aggressive aliasing):
//   [0,32M)     Q   (fp16)
//   [32M,64M)   Kb  (fp16)
//   [64M,96M)   Vt  (fp16)    <- x16 lives here until transpose_v runs
//   [96M,224M)  P   (fp16)    <- V in [96M,128M) until scores runs;
//                                W16 (6 MiB) in [218M,224M) until scores runs
// ---------------------------------------------------------------------------
extern "C" void kernel_launch(void* const* d_in, const int* in_sizes, int n_in,
                              void* d_out, int out_size, void* d_ws, size_t ws_size,
                              hipStream_t stream) {
    const float* x  = (const float*)d_in[0];
    const float* Wq = (const float*)d_in[1];
    const float* Wk = (const float*)d_in[2];
    const float* Wv = (const float*)d_in[3];
    float* out = (float*)d_out;

    char* ws = (char*)d_ws;
    const size_t MB = 1ull << 20;
    u16* Q   = (u16*)(ws);
    u16* Kb  = (u16*)(ws + 32 * MB);
    u16* Vt  = (u16*)(ws + 64 * MB);
    u16* P   = (u16*)(ws + 96 * MB);
    u16* V   = P;                                  // alias: dead before P written
    u16* x16 = Vt;                                 // alias: dead before Vt written
    u16* W16 = (u16*)(ws + 218 * MB);              // alias into P tail: dead before
                                                   // scores writes there

    dim3 blk(256);
    dim3 blk2(512);
    cvt_kernel <<<dim3(NB * S * D / 8 / 256), blk, 0, stream>>>(x,  x16, NB * S * D / 8);
    cvt_kernel <<<dim3(D * D / 8 / 256), blk, 0, stream>>>(Wq, W16,             D * D / 8);
    cvt_kernel <<<dim3(D * D / 8 / 256), blk, 0, stream>>>(Wk, W16 + (size_t)D * D, D * D / 8);
    cvt_kernel <<<dim3(D * D / 8 / 256), blk, 0, stream>>>(Wv, W16 + (size_t)2 * D * D, D * D / 8);

    qkv_kernel    <<<dim3(NB * S / 256, D / 256, 3), blk2, 0, stream>>>(x16, W16, Q, Kb, V);
    transpose_v   <<<dim3(NB * S / 64, D / 64), blk, 0, stream>>>(V, Vt);
    scores_kernel <<<dim3(S / 256, S / 256, NB), blk2, 0, stream>>>(Q, Kb, P);
    softmax_kernel<<<dim3(NB * S), blk, 0, stream>>>(P);
    pv_kernel     <<<dim3(S / 256, D / 256, NB), blk2, 0, stream>>>(P, Vt, x, out);
    normalize_kernel<<<dim3(NB * S), blk, 0, stream>>>(out);
}

// Round 5
// 516.586 us; speedup vs baseline: 1.0641x; 1.0641x over previous
//
#include <hip/hip_runtime.h>

typedef unsigned short u16;
typedef _Float16 half8 __attribute__((ext_vector_type(8)));
typedef __attribute__((ext_vector_type(4))) float f32x4;

constexpr int NB = 4;        // batch
constexpr int S  = 4096;     // sequence
constexpr int D  = 1024;     // model dim

__device__ __forceinline__ u16 h2u(_Float16 h) {
    union { _Float16 h; u16 u; } v; v.h = h; return v.u;
}

// Async global->LDS, 16 B per lane. LDS destination is wave-uniform
// base + lane*16 (lane-linear chunk order).
__device__ __forceinline__ void async16(const void* g, void* l) {
    __builtin_amdgcn_global_load_lds(
        (const __attribute__((address_space(1))) unsigned int*)g,
        (__attribute__((address_space(3))) unsigned int*)l, 16, 0, 0);
}

#define BAR()  __builtin_amdgcn_s_barrier()
#define SFEN() __builtin_amdgcn_sched_barrier(0)

// 16 MFMA for quadrant (QM,QN): 4 M-frags x 2 N-frags x 2 K-halves.
#define MF(AF, BF, QM, QN)                                                     \
  do {                                                                         \
    _Pragma("unroll") for (int m_ = 0; m_ < 4; ++m_)                           \
    _Pragma("unroll") for (int n_ = 0; n_ < 2; ++n_)                           \
    _Pragma("unroll") for (int k_ = 0; k_ < 2; ++k_)                           \
      acc[(QM)*4 + m_][(QN)*2 + n_] = __builtin_amdgcn_mfma_f32_16x16x32_f16(  \
          AF[m_][k_], BF[n_][k_], acc[(QM)*4 + m_][(QN)*2 + n_], 0, 0, 0);     \
  } while (0)

// Fragment reads off precomputed per-lane bases; (qm,m)/(qn,n) are
// compile-time -> fold into the ds_read_b128 immediate offset.
#define RDA(dst, bp0, bp1, qm)                                                 \
  _Pragma("unroll") for (int m_ = 0; m_ < 4; ++m_) {                           \
    dst[m_][0] = *(const half8*)(bp0 + (qm) * 4096 + m_ * 1024);               \
    dst[m_][1] = *(const half8*)(bp1 + (qm) * 4096 + m_ * 1024); }
#define RDB(dst, bp0, bp1, qn)                                                 \
  _Pragma("unroll") for (int n_ = 0; n_ < 2; ++n_) {                           \
    dst[n_][0] = *(const half8*)(bp0 + (qn) * 2048 + n_ * 1024);               \
    dst[n_][1] = *(const half8*)(bp1 + (qn) * 2048 + n_ * 1024); }

// ---------------------------------------------------------------------------
// One K-tile, ONE barrier. R = buffer computed this tile (read bases
// rA0/rA1/rB0/rB1); O = other buffer, fully staged here @ KN (tile t+1).
//
// CROSS-WAVE PUBLICATION INVARIANT (round-4 lesson): vmcnt is PER-WAVE, but
// slots are staged cooperatively. A dependent read is only safe after
// {every wave: vmcnt wait} -> barrier. Hence the ONLY wait-point is
// end-of-tile vmcnt(0) -> BAR, which publishes the WHOLE of O to all waves
// before the next tile's entry reads. No mid-tile waits, no reads of
// same-tile-staged data.
//
// The vmcnt(0) is structurally counted: the 8 loads it drains were issued
// at the START of this tile, ~2400 MFMA-cycles earlier (whole 64-MFMA block
// in between), so L2/HBM latency (~200-900cyc) is covered -> drain ~free.
// Overwrite safety: gloads into O issue after the entry barrier; previous
// tile's reads of O were consumed by in-order MFMAs before the previous
// end barrier. Sound under arbitrary intra-tile wave drift.
// Overlap: b1/a1 reads (16 of 24) sit between MFMA blocks -> compiler's
// progressive lgkmcnt hides them under MFMA issue.
// ---------------------------------------------------------------------------
#define TILE(OAd, OBd, rA0, rA1, rB0, rB1, KN)                                 \
  {                                                                            \
    RDA(a0, rA0, rA1, 0)                                                       \
    RDB(b0, rB0, rB1, 0)                                                       \
    issue(Am, OAd, rsA,      KN);                                              \
    issue(Am, OAd, rsA + 64, KN);                                              \
    issue(Bm, OBd, rsB,      KN);                                              \
    issue(Bm, OBd, rsB + 32, KN);                                              \
    __builtin_amdgcn_s_setprio(1);                                             \
    MF(a0, b0, 0, 0);                                                          \
    RDB(b1, rB0, rB1, 1)                                                       \
    MF(a0, b1, 0, 1);                                                          \
    RDA(a1, rA0, rA1, 1)                                                       \
    MF(a1, b0, 1, 0);                                                          \
    MF(a1, b1, 1, 1);                                                          \
    __builtin_amdgcn_s_setprio(0);                                             \
    asm volatile("s_waitcnt vmcnt(0)" ::: "memory");                           \
    BAR(); SFEN();                                                             \
  }

// ---------------------------------------------------------------------------
// 256x256x(K) NT GEMM core, one-barrier-per-K-tile schedule.
// A [256 x K] fp16 row-major (pre-offset), B [256 x K] fp16 row-major
// (pre-offset). 512 threads = 8 waves (2M x 4N); per-wave 128x64 output,
// acc[8][4] f32x4. LDS: double buffer x (A[256][64] + B[256][64]) = 128 KiB.
//
// Row = 64 halfs = 128 B = full bank period. XOR swizzle: global chunk gc of
// row r stored at chunk gc ^ (r&7), applied on the SOURCE address
// (lane-linear LDS dest, required by global_load_lds). Read addresses come
// from 8 precomputed per-lane bases (A/B x kk x buffer); (qm,m)/(qn,n)
// become ds_read immediate offsets (max 14336 B < 64 KiB).
//
// Fragment layouts (HW-verified, carried from the 128^2 kernel):
//   A: lane holds A[m=lane&15][kk*32 + (lane>>4)*8 + j]
//   C: acc[mi][ni][r] = C[wm*128+mi*16+(lane>>4)*4+r][wn*64+ni*16+(lane&15)]
// ---------------------------------------------------------------------------
__device__ __forceinline__ void gemm256(
    const u16* __restrict__ Am, const u16* __restrict__ Bm, const int K,
    u16* lds, f32x4 acc[8][4])
{
    const int tid  = threadIdx.x;
    const int lane = tid & 63;
    const int w    = tid >> 6;          // 0..7
    const int wm   = w >> 2;            // 0..1
    const int wn   = w & 3;             // 0..3
    const int quad = lane >> 4;
    const int lrow = lane & 15;
    const int s7   = lrow & 7;
    const int rl   = lane >> 3;                    // staging row-in-group
    const int gc8  = ((lane & 7) ^ rl) * 8;        // swizzled source chunk
    const int rsA  = (wm << 7) + ((w & 3) << 4);   // A slot row-start
    const int rsB  = ((w >> 1) << 6) + ((w & 1) << 4);   // B slot row-start

    u16* const As0 = lds;
    u16* const Bs0 = lds + 16384;
    u16* const As1 = lds + 32768;
    u16* const Bs1 = lds + 49152;

    // Per-lane read bases (halfs). lt0/lt1 = lane term for kk=0/1.
    const int lt0 = lrow * 64 + ((quad ^ s7) * 8);
    const int lt1 = lrow * 64 + (((4 + quad) ^ s7) * 8);
    const u16* const bA00 = As0 + wm * 8192 + lt0;
    const u16* const bA01 = As0 + wm * 8192 + lt1;
    const u16* const bA10 = As1 + wm * 8192 + lt0;
    const u16* const bA11 = As1 + wm * 8192 + lt1;
    const u16* const bB00 = Bs0 + wn * 4096 + lt0;
    const u16* const bB01 = Bs0 + wn * 4096 + lt1;
    const u16* const bB10 = Bs1 + wn * 4096 + lt0;
    const u16* const bB11 = Bs1 + wn * 4096 + lt1;

    auto issue = [&](const u16* M, u16* dst, int rs, int k0) {
        async16(M + (size_t)(rs + rl) * K + k0 + gc8,
                dst + (size_t)(rs)     * 64 + (size_t)lane * 8);
        async16(M + (size_t)(rs + 8 + rl) * K + k0 + gc8,
                dst + (size_t)(rs + 8) * 64 + (size_t)lane * 8);
    };

    // Prologue: stage buf0 fully; publish to all waves (vmcnt(0) -> BAR).
    issue(Am, As0, rsA,      0);
    issue(Am, As0, rsA + 64, 0);
    issue(Bm, Bs0, rsB,      0);
    issue(Bm, Bs0, rsB + 32, 0);
    asm volatile("s_waitcnt vmcnt(0)" ::: "memory");
    BAR(); SFEN();

    half8 a0[4][2], a1[4][2], b0[2][2], b1[2][2];
    const int km = K - 1;               // K is a power of two (1024 / 4096)
    const int NI = K >> 7;              // 2 K-tiles (BK=64) per iteration
    for (int it = 0; it < NI; ++it) {
        const int kb  = it << 7;
        const int t1k = (kb + 64)  & km;      // real
        const int t2k = (kb + 128) & km;      // wraps to dummy on last iter
        TILE(As1, Bs1, bA00, bA01, bB00, bB01, t1k)   // compute buf0, stage buf1
        TILE(As0, Bs0, bA10, bA11, bB10, bB11, t2k)   // compute buf1, stage buf0
    }
    // Final tile's (wrapped) prefetches are fully drained by its vmcnt(0);
    // they only touch LDS slots that are never read again.
}

// ---------------------------------------------------------------------------
// 0) fp32 -> fp16 cast, 8 elems/thread
// ---------------------------------------------------------------------------
__global__ __launch_bounds__(256) void cvt_kernel(
    const float* __restrict__ in, u16* __restrict__ out, int n8)
{
    const int i = blockIdx.x * 256 + threadIdx.x;
    if (i >= n8) return;
    const float4 a = *(const float4*)(in + (size_t)i * 8);
    const float4 b = *(const float4*)(in + (size_t)i * 8 + 4);
    half8 h;
    h[0] = (_Float16)a.x; h[1] = (_Float16)a.y;
    h[2] = (_Float16)a.z; h[3] = (_Float16)a.w;
    h[4] = (_Float16)b.x; h[5] = (_Float16)b.y;
    h[6] = (_Float16)b.z; h[7] = (_Float16)b.w;
    *(half8*)(out + (size_t)i * 8) = h;
}

// ---------------------------------------------------------------------------
// 1) QKV projection: out[s,e] = sum_d x16[s,d] * W16[e,d]  (NT, K=D)
// grid (64, 4, 3); z picks {Wq,Wk,Wv} -> {Q,K,V} (fp16). XCD-chunk swizzle.
// ---------------------------------------------------------------------------
__global__ __launch_bounds__(512, 2) void qkv_kernel(
    const u16* __restrict__ x16, const u16* __restrict__ W16,
    u16* __restrict__ Q, u16* __restrict__ Kb, u16* __restrict__ V)
{
    __shared__ __align__(16) u16 lds[65536];          // 128 KiB
    // bijective XCD swizzle: nwg=768, cpx=96
    const int lin = blockIdx.x + (blockIdx.y << 6) + (blockIdx.z << 8);
    const int swz = (lin & 7) * 96 + (lin >> 3);
    const int bx = swz & 63, by = (swz >> 6) & 3, bz = swz >> 8;

    const int tile_m = bx * 256;
    const int tile_n = by * 256;
    const u16* W = W16 + (size_t)bz * D * D;
    u16* out = (bz == 0) ? Q : (bz == 1) ? Kb : V;

    f32x4 acc[8][4];
#pragma unroll
    for (int i = 0; i < 8; ++i)
#pragma unroll
        for (int j = 0; j < 4; ++j) acc[i][j] = (f32x4)0.0f;

    gemm256(x16 + (size_t)tile_m * D, W + (size_t)tile_n * D, D, lds, acc);

    const int tid = threadIdx.x, lane = tid & 63, w = tid >> 6;
    const int quad = lane >> 4, lrow = lane & 15;
    const int wm = w >> 2, wn = w & 3;
#pragma unroll
    for (int mi = 0; mi < 8; ++mi)
#pragma unroll
        for (int r = 0; r < 4; ++r) {
            const int row = tile_m + wm * 128 + mi * 16 + quad * 4 + r;
#pragma unroll
            for (int ni = 0; ni < 4; ++ni) {
                const int col = tile_n + wn * 64 + ni * 16 + lrow;
                out[(size_t)row * D + col] = h2u((_Float16)acc[mi][ni][r]);
            }
        }
}

// ---------------------------------------------------------------------------
// 2) Transpose V [NB*S x D] -> Vt [NB][D][S] (64x64 LDS tiles, fp16 bits)
// ---------------------------------------------------------------------------
__global__ __launch_bounds__(256) void transpose_v(
    const u16* __restrict__ V, u16* __restrict__ Vt)
{
    __shared__ u16 t[64][72];                      // 144B row stride (16B-mult)
    const int sg = blockIdx.x * 64;                // global row (b,s)
    const int b  = sg >> 12;
    const int s0 = sg & (S - 1);
    const int e0 = blockIdx.y * 64;
    const int tid = threadIdx.x;
#pragma unroll
    for (int p = 0; p < 2; ++p) {
        const int v  = tid + 256 * p;              // 0..511
        const int sr = v >> 3, sc = (v & 7) * 8;
        half8 vec = *(const half8*)(V + (size_t)(sg + sr) * D + e0 + sc);
        *(half8*)&t[sr][sc] = vec;
    }
    __syncthreads();
#pragma unroll
    for (int p = 0; p < 2; ++p) {
        const int v  = tid + 256 * p;
        const int e  = v >> 3, s8 = (v & 7) * 8;
        u16 o[8];
#pragma unroll
        for (int j = 0; j < 8; ++j) o[j] = t[s8 + j][e];
        *(uint4*)(Vt + (size_t)b * D * S + (size_t)(e0 + e) * S + s0 + s8) = *(const uint4*)o;
    }
}

// ---------------------------------------------------------------------------
// 3) scores: P[b][q][k] = Q_b[q,:] . K_b[k,:]   (NT, K=D), grid (16,16,4)
// ---------------------------------------------------------------------------
__global__ __launch_bounds__(512, 2) void scores_kernel(
    const u16* __restrict__ Q, const u16* __restrict__ Kb, u16* __restrict__ P)
{
    __shared__ __align__(16) u16 lds[65536];
    // bijective XCD swizzle: nwg=1024, cpx=128
    const int lin = blockIdx.x + ((blockIdx.y + (blockIdx.z << 4)) << 4);
    const int swz = ((lin & 7) << 7) + (lin >> 3);
    const int bx = swz & 15, by = (swz >> 4) & 15, bz = swz >> 8;

    const int b = bz;
    const int tile_m = bx * 256;
    const int tile_n = by * 256;
    const u16* Ab = Q  + (size_t)b * S * D + (size_t)tile_m * D;
    const u16* Bv = Kb + (size_t)b * S * D + (size_t)tile_n * D;

    f32x4 acc[8][4];
#pragma unroll
    for (int i = 0; i < 8; ++i)
#pragma unroll
        for (int j = 0; j < 4; ++j) acc[i][j] = (f32x4)0.0f;

    gemm256(Ab, Bv, D, lds, acc);

    u16* Pb = P + (size_t)b * S * S;
    const int tid = threadIdx.x, lane = tid & 63, w = tid >> 6;
    const int quad = lane >> 4, lrow = lane & 15;
    const int wm = w >> 2, wn = w & 3;
#pragma unroll
    for (int mi = 0; mi < 8; ++mi)
#pragma unroll
        for (int r = 0; r < 4; ++r) {
            const int row = tile_m + wm * 128 + mi * 16 + quad * 4 + r;
#pragma unroll
            for (int ni = 0; ni < 4; ++ni) {
                const int col = tile_n + wn * 64 + ni * 16 + lrow;
                Pb[(size_t)row * S + col] = h2u((_Float16)acc[mi][ni][r]);
            }
        }
}

// ---------------------------------------------------------------------------
// 4) softmax over each row of P (4096 fp16), in place. 256 thr x 16 elems.
// ---------------------------------------------------------------------------
__global__ __launch_bounds__(256) void softmax_kernel(u16* __restrict__ P)
{
    const size_t row = blockIdx.x;                 // 0..NB*S-1 (flat: stride S)
    u16* p = P + row * S;
    const int tid = threadIdx.x;

    half8 h0 = *(const half8*)(p + tid * 16);
    half8 h1 = *(const half8*)(p + tid * 16 + 8);
    float v[16];
#pragma unroll
    for (int i = 0; i < 8; ++i) { v[i] = (float)h0[i]; v[8 + i] = (float)h1[i]; }

    float m = v[0];
#pragma unroll
    for (int i = 1; i < 16; ++i) m = fmaxf(m, v[i]);
#pragma unroll
    for (int off = 32; off > 0; off >>= 1) m = fmaxf(m, __shfl_xor(m, off));

    __shared__ float redm[4], reds[4];
    const int wid = tid >> 6;
    if ((tid & 63) == 0) redm[wid] = m;
    __syncthreads();
    m = fmaxf(fmaxf(redm[0], redm[1]), fmaxf(redm[2], redm[3]));

    float e[16], s = 0.f;
#pragma unroll
    for (int i = 0; i < 16; ++i) { e[i] = __expf(v[i] - m); s += e[i]; }
#pragma unroll
    for (int off = 32; off > 0; off >>= 1) s += __shfl_xor(s, off);
    if ((tid & 63) == 0) reds[wid] = s;
    __syncthreads();
    s = reds[0] + reds[1] + reds[2] + reds[3];
    const float inv = 1.0f / s;                    // s >= 1 always

#pragma unroll
    for (int i = 0; i < 8; ++i) {
        h0[i] = (_Float16)(e[i] * inv);
        h1[i] = (_Float16)(e[8 + i] * inv);
    }
    *(half8*)(p + tid * 16)     = h0;
    *(half8*)(p + tid * 16 + 8) = h1;
}

// ---------------------------------------------------------------------------
// 5) PV: y[b,q,d] = sum_k P[b,q,k]*Vt[b,d,k] + x[b,q,d]; y -> d_out (fp32).
//    grid (16,4,4). Row norms recomputed later by normalize_kernel.
// ---------------------------------------------------------------------------
__global__ __launch_bounds__(512, 2) void pv_kernel(
    const u16* __restrict__ P, const u16* __restrict__ Vt,
    const float* __restrict__ x, float* __restrict__ y)
{
    __shared__ __align__(16) u16 lds[65536];
    // bijective XCD swizzle: nwg=256, cpx=32
    const int lin = blockIdx.x + (blockIdx.y << 4) + (blockIdx.z << 6);
    const int swz = ((lin & 7) << 5) + (lin >> 3);
    const int bx = swz & 15, by = (swz >> 4) & 3, bz = swz >> 6;

    const int b = bz;
    const int tile_m = bx * 256;                   // query tile
    const int tile_n = by * 256;                   // d tile
    const u16* Ab = P  + (size_t)b * S * S + (size_t)tile_m * S;
    const u16* Bv = Vt + (size_t)b * D * S + (size_t)tile_n * S;

    f32x4 acc[8][4];
#pragma unroll
    for (int i = 0; i < 8; ++i)
#pragma unroll
        for (int j = 0; j < 4; ++j) acc[i][j] = (f32x4)0.0f;

    gemm256(Ab, Bv, S, lds, acc);

    const int tid = threadIdx.x, lane = tid & 63, w = tid >> 6;
    const int quad = lane >> 4, lrow = lane & 15;
    const int wm = w >> 2, wn = w & 3;

#pragma unroll
    for (int mi = 0; mi < 8; ++mi)
#pragma unroll
        for (int r = 0; r < 4; ++r) {
            const int row = tile_m + wm * 128 + mi * 16 + quad * 4 + r;
            const size_t base = ((size_t)b * S + row) * D;
#pragma unroll
            for (int ni = 0; ni < 4; ++ni) {
                const int col = tile_n + wn * 64 + ni * 16 + lrow;
                y[base + col] = acc[mi][ni][r] + x[base + col];
            }
        }
}

// ---------------------------------------------------------------------------
// 6) normalize rows of y (fp32) in place: block per row, 256 thr x float4.
// ---------------------------------------------------------------------------
__global__ __launch_bounds__(256) void normalize_kernel(float* __restrict__ y)
{
    const size_t row = blockIdx.x;
    const int tid = threadIdx.x;
    float4* p = (float4*)(y + row * D) + tid;

    float4 v = *p;
    float ss = v.x * v.x + v.y * v.y + v.z * v.z + v.w * v.w;
#pragma unroll
    for (int off = 32; off > 0; off >>= 1) ss += __shfl_xor(ss, off);

    __shared__ float red[4];
    const int wid = tid >> 6;
    if ((tid & 63) == 0) red[wid] = ss;
    __syncthreads();
    const float inv = rsqrtf(red[0] + red[1] + red[2] + red[3]);

    v.x *= inv; v.y *= inv; v.z *= inv; v.w *= inv;
    *p = v;
}

// ---------------------------------------------------------------------------
// Workspace layout (224 MiB total, aggressive aliasing):
//   [0,32M)     Q   (fp16)
//   [32M,64M)   Kb  (fp16)
//   [64M,96M)   Vt  (fp16)    <- x16 lives here until transpose_v runs
//   [96M,224M)  P   (fp16)    <- V in [96M,128M) until scores runs;
//                                W16 (6 MiB) in [218M,224M) until scores runs
// ---------------------------------------------------------------------------
extern "C" void kernel_launch(void* const* d_in, const int* in_sizes, int n_in,
                              void* d_out, int out_size, void* d_ws, size_t ws_size,
                              hipStream_t stream) {
    const float* x  = (const float*)d_in[0];
    const float* Wq = (const float*)d_in[1];
    const float* Wk = (const float*)d_in[2];
    const float* Wv = (const float*)d_in[3];
    float* out = (float*)d_out;

    char* ws = (char*)d_ws;
    const size_t MB = 1ull << 20;
    u16* Q   = (u16*)(ws);
    u16* Kb  = (u16*)(ws + 32 * MB);
    u16* Vt  = (u16*)(ws + 64 * MB);
    u16* P   = (u16*)(ws + 96 * MB);
    u16* V   = P;                                  // alias: dead before P written
    u16* x16 = Vt;                                 // alias: dead before Vt written
    u16* W16 = (u16*)(ws + 218 * MB);              // alias into P tail: dead before
                                                   // scores writes there

    dim3 blk(256);
    dim3 blk2(512);
    cvt_kernel <<<dim3(NB * S * D / 8 / 256), blk, 0, stream>>>(x,  x16, NB * S * D / 8);
    cvt_kernel <<<dim3(D * D / 8 / 256), blk, 0, stream>>>(Wq, W16,             D * D / 8);
    cvt_kernel <<<dim3(D * D / 8 / 256), blk, 0, stream>>>(Wk, W16 + (size_t)D * D, D * D / 8);
    cvt_kernel <<<dim3(D * D / 8 / 256), blk, 0, stream>>>(Wv, W16 + (size_t)2 * D * D, D * D / 8);

    qkv_kernel    <<<dim3(NB * S / 256, D / 256, 3), blk2, 0, stream>>>(x16, W16, Q, Kb, V);
    transpose_v   <<<dim3(NB * S / 64, D / 64), blk, 0, stream>>>(V, Vt);
    scores_kernel <<<dim3(S / 256, S / 256, NB), blk2, 0, stream>>>(Q, Kb, P);
    softmax_kernel<<<dim3(NB * S), blk, 0, stream>>>(P);
    pv_kernel     <<<dim3(S / 256, D / 256, NB), blk2, 0, stream>>>(P, Vt, x, out);
    normalize_kernel<<<dim3(NB * S), blk, 0, stream>>>(out);
}